// Round 1
// baseline (1891.663 us; speedup 1.0000x reference)
//
#include <hip/hip_runtime.h>

// ---------------------------------------------------------------------------
// GCN forward: 4x (GraphConv norm='both') on N=50000, E=800000, 256->512->512->512->40
// Strategy:
//   c_src = outdeg^-1/2, c_dst = indeg^-1/2  (CSR-by-dst built per call)
//   L1: agg256(x) -> GEMM 256x512 +b +relu
//   L2: agg512    -> GEMM 512x512 +b +relu
//   L3: agg512    -> GEMM 512x512 +b +relu
//   L4: GEMM 512x40 (no bias) -> agg40 +b4
// All fp32 (no fp32 MFMA on CDNA4; VALU GEMM this round).
// ---------------------------------------------------------------------------

#define GCN_N 50000
#define GCN_E 800000

__global__ void hist_kernel(const int* __restrict__ src, const int* __restrict__ dst,
                            int* __restrict__ deg_src, int* __restrict__ deg_dst, int E) {
  int i = blockIdx.x * blockDim.x + threadIdx.x;
  if (i < E) {
    atomicAdd(&deg_src[src[i]], 1);
    atomicAdd(&deg_dst[dst[i]], 1);
  }
}

__global__ void cinv_kernel(const int* __restrict__ deg_src, const int* __restrict__ deg_dst,
                            float* __restrict__ c_src, float* __restrict__ c_dst, int n) {
  int i = blockIdx.x * blockDim.x + threadIdx.x;
  if (i < n) {
    int ds = deg_src[i];
    int dd = deg_dst[i];
    c_src[i] = ds > 0 ? 1.0f / sqrtf((float)ds) : 0.0f;
    c_dst[i] = dd > 0 ? 1.0f / sqrtf((float)dd) : 0.0f;
  }
}

// Single-block exclusive scan of deg (n elems) -> row_ptr[0..n], also copies to cursor.
__global__ void scan_kernel(const int* __restrict__ deg, int* __restrict__ row_ptr,
                            int* __restrict__ cursor, int n) {
  __shared__ int wsum[16];
  __shared__ int s_carry;
  int lane = threadIdx.x & 63;
  int wid = threadIdx.x >> 6;
  if (threadIdx.x == 0) s_carry = 0;
  __syncthreads();
  for (int base = 0; base < n; base += 1024) {
    int i = base + (int)threadIdx.x;
    int v = (i < n) ? deg[i] : 0;
    int x = v;
    #pragma unroll
    for (int off = 1; off < 64; off <<= 1) {
      int y = __shfl_up(x, off, 64);
      if (lane >= off) x += y;
    }
    if (lane == 63) wsum[wid] = x;
    __syncthreads();
    int woff = s_carry;
    for (int w = 0; w < wid; ++w) woff += wsum[w];
    int incl = woff + x;
    if (i < n) {
      row_ptr[i] = incl - v;
      cursor[i] = incl - v;
    }
    __syncthreads();
    if (threadIdx.x == 1023) s_carry = incl;
    __syncthreads();
  }
  if (threadIdx.x == 0) row_ptr[n] = s_carry;
}

__global__ void fill_csr_kernel(const int* __restrict__ src, const int* __restrict__ dst,
                                int* __restrict__ cursor, int* __restrict__ csr_src, int E) {
  int i = blockIdx.x * blockDim.x + threadIdx.x;
  if (i < E) {
    int slot = atomicAdd(&cursor[dst[i]], 1);
    csr_src[slot] = src[i];
  }
}

// One block per dst node; thread t owns float4 column group t (t < F4).
// out[d][:] = c_dst[d] * sum_{e in CSR row d} c_src[src_e] * in[src_e][:]  (+ bias)
template <bool BIAS>
__global__ void aggregate_kernel(const float* __restrict__ in, float* __restrict__ out,
                                 const int* __restrict__ row_ptr, const int* __restrict__ csr_src,
                                 const float* __restrict__ c_src, const float* __restrict__ c_dst,
                                 const float* __restrict__ bias, int F4) {
  int d = blockIdx.x;
  int t = threadIdx.x;
  if (t >= F4) return;
  int beg = row_ptr[d];
  int end = row_ptr[d + 1];
  const float4* in4 = (const float4*)in;
  float4 acc = make_float4(0.f, 0.f, 0.f, 0.f);
  for (int k = beg; k < end; ++k) {
    int s = csr_src[k];
    float cs = c_src[s];
    float4 v = in4[(size_t)s * F4 + t];
    acc.x += cs * v.x;
    acc.y += cs * v.y;
    acc.z += cs * v.z;
    acc.w += cs * v.w;
  }
  float cd = c_dst[d];
  acc.x *= cd; acc.y *= cd; acc.z *= cd; acc.w *= cd;
  if (BIAS) {
    float4 b = ((const float4*)bias)[t];
    acc.x += b.x; acc.y += b.y; acc.z += b.z; acc.w += b.w;
  }
  ((float4*)out)[(size_t)d * F4 + t] = acc;
}

// fp32 VALU GEMM: C[M x N] = A[M x K] * W[K x N] (+bias, relu).
// 128x128 tile, BK=16, 256 threads, 8x8 per thread.
template <bool BIASRELU>
__global__ __launch_bounds__(256) void gemm_kernel(const float* __restrict__ A,
                                                   const float* __restrict__ W,
                                                   const float* __restrict__ bias,
                                                   float* __restrict__ C,
                                                   int M, int K, int N) {
  __shared__ float As[16][128 + 4];
  __shared__ float Bs[16][128 + 4];
  int tid = threadIdx.x;
  int tx = tid & 15;   // col group
  int ty = tid >> 4;   // row group
  int bm = blockIdx.x * 128;
  int bn = blockIdx.y * 128;

  float acc[8][8];
  #pragma unroll
  for (int i = 0; i < 8; ++i)
    #pragma unroll
    for (int j = 0; j < 8; ++j) acc[i][j] = 0.f;

  int ar = tid >> 2;          // 0..63 (row within tile half)
  int akq = (tid & 3) << 2;   // k sub-offset 0,4,8,12
  int bkk = tid >> 4;         // 0..15 (k row)
  int bcq = (tid & 15) << 2;  // col sub-offset

  for (int k0 = 0; k0 < K; k0 += 16) {
    #pragma unroll
    for (int half = 0; half < 2; ++half) {
      int r = ar + half * 64;
      int grow = bm + r;
      float4 v = make_float4(0.f, 0.f, 0.f, 0.f);
      if (grow < M) v = *(const float4*)&A[(size_t)grow * K + k0 + akq];
      As[akq + 0][r] = v.x;
      As[akq + 1][r] = v.y;
      As[akq + 2][r] = v.z;
      As[akq + 3][r] = v.w;
    }
    #pragma unroll
    for (int half = 0; half < 2; ++half) {
      int c = bcq + half * 64;
      int gc = bn + c;
      float4 v = make_float4(0.f, 0.f, 0.f, 0.f);
      if (gc + 3 < N) v = *(const float4*)&W[(size_t)(k0 + bkk) * N + gc];
      *(float4*)&Bs[bkk][c] = v;
    }
    __syncthreads();
    #pragma unroll
    for (int kk = 0; kk < 16; ++kk) {
      float4 a0 = *(const float4*)&As[kk][ty * 4];
      float4 a1 = *(const float4*)&As[kk][ty * 4 + 64];
      float4 b0 = *(const float4*)&Bs[kk][tx * 4];
      float4 b1 = *(const float4*)&Bs[kk][tx * 4 + 64];
      float a[8] = {a0.x, a0.y, a0.z, a0.w, a1.x, a1.y, a1.z, a1.w};
      float b[8] = {b0.x, b0.y, b0.z, b0.w, b1.x, b1.y, b1.z, b1.w};
      #pragma unroll
      for (int i = 0; i < 8; ++i)
        #pragma unroll
        for (int j = 0; j < 8; ++j) acc[i][j] = fmaf(a[i], b[j], acc[i][j]);
    }
    __syncthreads();
  }

  #pragma unroll
  for (int i = 0; i < 8; ++i) {
    int r = bm + (i < 4 ? ty * 4 + i : 64 + ty * 4 + (i - 4));
    if (r >= M) continue;
    #pragma unroll
    for (int j = 0; j < 8; ++j) {
      int c = bn + (j < 4 ? tx * 4 + j : 64 + tx * 4 + (j - 4));
      if (c >= N) continue;
      float v = acc[i][j];
      if (BIASRELU) {
        v += bias[c];
        v = v > 0.f ? v : 0.f;
      }
      C[(size_t)r * N + c] = v;
    }
  }
}

extern "C" void kernel_launch(void* const* d_in, const int* in_sizes, int n_in,
                              void* d_out, int out_size, void* d_ws, size_t ws_size,
                              hipStream_t stream) {
  const float* x  = (const float*)d_in[0];
  const int* src  = (const int*)d_in[1];
  const int* dst  = (const int*)d_in[2];
  const float* W1 = (const float*)d_in[3];
  const float* b1 = (const float*)d_in[4];
  const float* W2 = (const float*)d_in[5];
  const float* b2 = (const float*)d_in[6];
  const float* W3 = (const float*)d_in[7];
  const float* b3 = (const float*)d_in[8];
  const float* W4 = (const float*)d_in[9];
  const float* b4 = (const float*)d_in[10];
  float* out = (float*)d_out;

  const int N = GCN_N, E = GCN_E;

  char* ws = (char*)d_ws;
  size_t off = 0;
  float* bufA = (float*)(ws + off); off += (size_t)N * 512 * 4;
  float* bufB = (float*)(ws + off); off += (size_t)N * 512 * 4;
  float* c_src = (float*)(ws + off); off += (size_t)N * 4;
  float* c_dst = (float*)(ws + off); off += (size_t)N * 4;
  int* row_ptr = (int*)(ws + off); off += (size_t)(N + 1) * 4;
  int* csr_src = (int*)(ws + off); off += (size_t)E * 4;
  // Transients live in bufA's space (bufA is first written only after CSR build).
  int* deg_src = (int*)bufA;
  int* deg_dst = deg_src + N;
  int* cursor  = deg_dst + N;

  hipMemsetAsync(deg_src, 0, (size_t)2 * N * 4, stream);
  hist_kernel<<<(E + 255) / 256, 256, 0, stream>>>(src, dst, deg_src, deg_dst, E);
  cinv_kernel<<<(N + 255) / 256, 256, 0, stream>>>(deg_src, deg_dst, c_src, c_dst, N);
  scan_kernel<<<1, 1024, 0, stream>>>(deg_dst, row_ptr, cursor, N);
  fill_csr_kernel<<<(E + 255) / 256, 256, 0, stream>>>(src, dst, cursor, csr_src, E);

  dim3 blk(256);
  int gm = (N + 127) / 128;  // 391

  // Layer 1: aggregate in 256-dim, then GEMM 256->512 (+b1, relu)
  aggregate_kernel<false><<<N, 64, 0, stream>>>(x, bufA, row_ptr, csr_src, c_src, c_dst, nullptr, 64);
  gemm_kernel<true><<<dim3(gm, 4), blk, 0, stream>>>(bufA, W1, b1, bufB, N, 256, 512);

  // Layer 2
  aggregate_kernel<false><<<N, 128, 0, stream>>>(bufB, bufA, row_ptr, csr_src, c_src, c_dst, nullptr, 128);
  gemm_kernel<true><<<dim3(gm, 4), blk, 0, stream>>>(bufA, W2, b2, bufB, N, 512, 512);

  // Layer 3
  aggregate_kernel<false><<<N, 128, 0, stream>>>(bufB, bufA, row_ptr, csr_src, c_src, c_dst, nullptr, 128);
  gemm_kernel<true><<<dim3(gm, 4), blk, 0, stream>>>(bufA, W3, b3, bufB, N, 512, 512);

  // Layer 4: GEMM 512->40 (no bias/act), then aggregate in 40-dim (+b4)
  gemm_kernel<false><<<dim3(gm, 1), blk, 0, stream>>>(bufB, W4, nullptr, bufA, N, 512, 40);
  aggregate_kernel<true><<<N, 64, 0, stream>>>(bufA, out, row_ptr, csr_src, c_src, c_dst, b4, 10);
}

// Round 2
// 1310.721 us; speedup vs baseline: 1.4432x; 1.4432x over previous
//
#include <hip/hip_runtime.h>
#include <hip/hip_bf16.h>

// ---------------------------------------------------------------------------
// GCN forward, 4x GraphConv norm='both'. N=50000, E=800000, 256->512->512->512->40
//   L1: agg256(x)->split  -> MFMA GEMM 256x512 +b +relu (fp32 out)
//   L2: agg512->split     -> MFMA GEMM 512x512 +b +relu
//   L3: agg512->split     -> MFMA GEMM 512x512 +b +relu
//   L4: VALU GEMM 512x40  -> agg40 +b4
// GEMMs use split-bf16 (hi+lo) x3-MFMA for ~fp32 accuracy on matrix cores.
// ---------------------------------------------------------------------------

#define GCN_N 50000
#define GCN_E 800000

typedef unsigned short u16;
typedef __attribute__((ext_vector_type(8))) short bf16x8;
typedef __attribute__((ext_vector_type(4))) float f32x4;

__device__ __forceinline__ void gload_lds16(const void* g, void* l) {
  __builtin_amdgcn_global_load_lds((const __attribute__((address_space(1))) void*)g,
                                   (__attribute__((address_space(3))) void*)l, 16, 0, 0);
}

__device__ __forceinline__ void bsplit(float v, u16& h, u16& l) {
  __hip_bfloat16 bh = __float2bfloat16(v);   // RNE
  float fh = __bfloat162float(bh);
  __hip_bfloat16 bl = __float2bfloat16(v - fh);
  h = __builtin_bit_cast(u16, bh);
  l = __builtin_bit_cast(u16, bl);
}

// ---------------- CSR build ----------------

__global__ void hist_kernel(const int* __restrict__ src, const int* __restrict__ dst,
                            int* __restrict__ deg_src, int* __restrict__ deg_dst, int E) {
  int i = blockIdx.x * blockDim.x + threadIdx.x;
  if (i < E) {
    atomicAdd(&deg_src[src[i]], 1);
    atomicAdd(&deg_dst[dst[i]], 1);
  }
}

__global__ void cinv_kernel(const int* __restrict__ deg_src, const int* __restrict__ deg_dst,
                            float* __restrict__ c_src, float* __restrict__ c_dst, int n) {
  int i = blockIdx.x * blockDim.x + threadIdx.x;
  if (i < n) {
    int ds = deg_src[i];
    int dd = deg_dst[i];
    c_src[i] = ds > 0 ? 1.0f / sqrtf((float)ds) : 0.0f;
    c_dst[i] = dd > 0 ? 1.0f / sqrtf((float)dd) : 0.0f;
  }
}

__global__ void scan_kernel(const int* __restrict__ deg, int* __restrict__ row_ptr,
                            int* __restrict__ cursor, int n) {
  __shared__ int wsum[16];
  __shared__ int s_carry;
  int lane = threadIdx.x & 63;
  int wid = threadIdx.x >> 6;
  if (threadIdx.x == 0) s_carry = 0;
  __syncthreads();
  for (int base = 0; base < n; base += 1024) {
    int i = base + (int)threadIdx.x;
    int v = (i < n) ? deg[i] : 0;
    int x = v;
    #pragma unroll
    for (int off = 1; off < 64; off <<= 1) {
      int y = __shfl_up(x, off, 64);
      if (lane >= off) x += y;
    }
    if (lane == 63) wsum[wid] = x;
    __syncthreads();
    int woff = s_carry;
    for (int w = 0; w < wid; ++w) woff += wsum[w];
    int incl = woff + x;
    if (i < n) {
      row_ptr[i] = incl - v;
      cursor[i] = incl - v;
    }
    __syncthreads();
    if (threadIdx.x == 1023) s_carry = incl;
    __syncthreads();
  }
  if (threadIdx.x == 0) row_ptr[n] = s_carry;
}

__global__ void fill_csr_kernel(const int* __restrict__ src, const int* __restrict__ dst,
                                int* __restrict__ cursor, int* __restrict__ csr_src, int E) {
  int i = blockIdx.x * blockDim.x + threadIdx.x;
  if (i < E) {
    int slot = atomicAdd(&cursor[dst[i]], 1);
    csr_src[slot] = src[i];
  }
}

// ---------------- aggregation ----------------

// fp32 in -> fp32 out (+bias). One block per dst node, thread t owns float4 col group t.
template <bool BIAS>
__global__ void aggregate_kernel(const float* __restrict__ in, float* __restrict__ out,
                                 const int* __restrict__ row_ptr, const int* __restrict__ csr_src,
                                 const float* __restrict__ c_src, const float* __restrict__ c_dst,
                                 const float* __restrict__ bias, int F4) {
  int d = blockIdx.x;
  int t = threadIdx.x;
  if (t >= F4) return;
  int beg = row_ptr[d];
  int end = row_ptr[d + 1];
  const float4* in4 = (const float4*)in;
  float4 acc = make_float4(0.f, 0.f, 0.f, 0.f);
  for (int k = beg; k < end; ++k) {
    int s = csr_src[k];
    float cs = c_src[s];
    float4 v = in4[(size_t)s * F4 + t];
    acc.x += cs * v.x;
    acc.y += cs * v.y;
    acc.z += cs * v.z;
    acc.w += cs * v.w;
  }
  float cd = c_dst[d];
  acc.x *= cd; acc.y *= cd; acc.z *= cd; acc.w *= cd;
  if (BIAS) {
    float4 b = ((const float4*)bias)[t];
    acc.x += b.x; acc.y += b.y; acc.z += b.z; acc.w += b.w;
  }
  ((float4*)out)[(size_t)d * F4 + t] = acc;
}

// fp32 in -> split bf16 hi/lo out (feeds MFMA GEMM A operand).
__global__ void agg_split_kernel(const float* __restrict__ in,
                                 u16* __restrict__ oh, u16* __restrict__ ol,
                                 const int* __restrict__ row_ptr, const int* __restrict__ csr_src,
                                 const float* __restrict__ c_src, const float* __restrict__ c_dst,
                                 int F4) {
  int d = blockIdx.x;
  int t = threadIdx.x;
  if (t >= F4) return;
  int beg = row_ptr[d];
  int end = row_ptr[d + 1];
  const float4* in4 = (const float4*)in;
  float4 acc = make_float4(0.f, 0.f, 0.f, 0.f);
  for (int k = beg; k < end; ++k) {
    int s = csr_src[k];
    float cs = c_src[s];
    float4 v = in4[(size_t)s * F4 + t];
    acc.x += cs * v.x;
    acc.y += cs * v.y;
    acc.z += cs * v.z;
    acc.w += cs * v.w;
  }
  float cd = c_dst[d];
  acc.x *= cd; acc.y *= cd; acc.z *= cd; acc.w *= cd;
  ushort4 hv, lv;
  bsplit(acc.x, hv.x, lv.x);
  bsplit(acc.y, hv.y, lv.y);
  bsplit(acc.z, hv.z, lv.z);
  bsplit(acc.w, hv.w, lv.w);
  ((ushort4*)oh)[(size_t)d * F4 + t] = hv;
  ((ushort4*)ol)[(size_t)d * F4 + t] = lv;
}

// ---------------- weight prep: W[K][N] fp32 -> Wt_hi/lo[N][K] bf16 ----------------

__global__ void prep_weight_kernel(const float* __restrict__ W, u16* __restrict__ th,
                                   u16* __restrict__ tl, int K, int N) {
  __shared__ float tile[32][33];
  int bn = blockIdx.x * 32, bk = blockIdx.y * 32;
  int tx = threadIdx.x, ty = threadIdx.y;  // (32, 8)
  #pragma unroll
  for (int i = 0; i < 4; ++i)
    tile[ty + i * 8][tx] = W[(size_t)(bk + ty + i * 8) * N + bn + tx];
  __syncthreads();
  #pragma unroll
  for (int i = 0; i < 4; ++i) {
    float v = tile[tx][ty + i * 8];           // = W[bk+tx][bn+ty+i*8]
    u16 h, l;
    bsplit(v, h, l);
    size_t o = (size_t)(bn + ty + i * 8) * K + bk + tx;  // Wt[n][k], k coalesced
    th[o] = h;
    tl[o] = l;
  }
}

// ---------------- split-bf16 MFMA GEMM ----------------
// C[M][N] = relu( (Ah+Al)[M][K] * (Bh+Bl)^T[N][K] + bias ), 3-term MFMA.
// 128x128 tile, BK=32, 256 thr = 4 waves (2x2), 4x4 16x16x32 frags per wave.
// Linear LDS + source-pre-swizzle (chunk ^= (row&3)^((row>>2)&3)) -> <=2-way conflicts.
__global__ __launch_bounds__(256) void mfma_gemm_kernel(
    const u16* __restrict__ Ah, const u16* __restrict__ Al,
    const u16* __restrict__ Bh, const u16* __restrict__ Bl,
    const float* __restrict__ bias, float* __restrict__ C,
    int M, int K, int N) {
  __shared__ u16 sAh[128 * 32], sAl[128 * 32], sBh[128 * 32], sBl[128 * 32];
  int t = threadIdx.x;
  int lane = t & 63, wid = t >> 6;
  int wr = wid >> 1, wc = wid & 1;
  int lr = lane & 15, ko = lane >> 4;
  int swz = (lr & 3) ^ ((lr >> 2) & 3);
  int koff = ((ko ^ swz) << 3);  // ushort units within a 32-elem row
  int bm = blockIdx.x * 128, bn = blockIdx.y * 128;

  f32x4 acc[4][4] = {};

  int aoff[4], boff[4];
  #pragma unroll
  for (int rb = 0; rb < 4; ++rb) {
    aoff[rb] = (wr * 64 + rb * 16 + lr) * 32 + koff;
    boff[rb] = (wc * 64 + rb * 16 + lr) * 32 + koff;
  }

  for (int k0 = 0; k0 < K; k0 += 32) {
    #pragma unroll
    for (int it = 0; it < 2; ++it) {
      int q = it * 256 + t;
      int row = q >> 2;
      int c = (q & 3) ^ ((row & 3) ^ ((row >> 2) & 3));
      int ldst = it * 2048 + wid * 512;  // ushort units, wave-uniform
      int gra = bm + row;
      if (gra >= M) gra = M - 1;
      size_t ga = (size_t)gra * K + k0 + c * 8;
      gload_lds16(Ah + ga, sAh + ldst);
      gload_lds16(Al + ga, sAl + ldst);
      size_t gb = (size_t)(bn + row) * K + k0 + c * 8;  // N%128==0 for MFMA layers
      gload_lds16(Bh + gb, sBh + ldst);
      gload_lds16(Bl + gb, sBl + ldst);
    }
    __syncthreads();
    bf16x8 ah[4], al[4], bh[4], bl[4];
    #pragma unroll
    for (int i = 0; i < 4; ++i) {
      ah[i] = *(const bf16x8*)(sAh + aoff[i]);
      al[i] = *(const bf16x8*)(sAl + aoff[i]);
      bh[i] = *(const bf16x8*)(sBh + boff[i]);
      bl[i] = *(const bf16x8*)(sBl + boff[i]);
    }
    #pragma unroll
    for (int i = 0; i < 4; ++i)
      #pragma unroll
      for (int j = 0; j < 4; ++j) {
        acc[i][j] = __builtin_amdgcn_mfma_f32_16x16x32_bf16(ah[i], bh[j], acc[i][j], 0, 0, 0);
        acc[i][j] = __builtin_amdgcn_mfma_f32_16x16x32_bf16(al[i], bh[j], acc[i][j], 0, 0, 0);
        acc[i][j] = __builtin_amdgcn_mfma_f32_16x16x32_bf16(ah[i], bl[j], acc[i][j], 0, 0, 0);
      }
    __syncthreads();
  }

  int r0 = (lane >> 4) << 2;
  #pragma unroll
  for (int i = 0; i < 4; ++i) {
    #pragma unroll
    for (int j = 0; j < 4; ++j) {
      int col = bn + wc * 64 + j * 16 + lr;
      float bv = bias[col];
      #pragma unroll
      for (int r = 0; r < 4; ++r) {
        int row = bm + wr * 64 + i * 16 + r0 + r;
        if (row < M) {
          float v = acc[i][j][r] + bv;
          v = v > 0.f ? v : 0.f;
          C[(size_t)row * N + col] = v;
        }
      }
    }
  }
}

// ---------------- fp32 VALU GEMM (layer 4, N=40) ----------------

template <bool BIASRELU>
__global__ __launch_bounds__(256) void gemm_kernel(const float* __restrict__ A,
                                                   const float* __restrict__ W,
                                                   const float* __restrict__ bias,
                                                   float* __restrict__ C,
                                                   int M, int K, int N) {
  __shared__ float As[16][128 + 4];
  __shared__ float Bs[16][128 + 4];
  int tid = threadIdx.x;
  int tx = tid & 15;
  int ty = tid >> 4;
  int bm = blockIdx.x * 128;
  int bn = blockIdx.y * 128;

  float acc[8][8];
  #pragma unroll
  for (int i = 0; i < 8; ++i)
    #pragma unroll
    for (int j = 0; j < 8; ++j) acc[i][j] = 0.f;

  int ar = tid >> 2;
  int akq = (tid & 3) << 2;
  int bkk = tid >> 4;
  int bcq = (tid & 15) << 2;

  for (int k0 = 0; k0 < K; k0 += 16) {
    #pragma unroll
    for (int half = 0; half < 2; ++half) {
      int r = ar + half * 64;
      int grow = bm + r;
      float4 v = make_float4(0.f, 0.f, 0.f, 0.f);
      if (grow < M) v = *(const float4*)&A[(size_t)grow * K + k0 + akq];
      As[akq + 0][r] = v.x;
      As[akq + 1][r] = v.y;
      As[akq + 2][r] = v.z;
      As[akq + 3][r] = v.w;
    }
    #pragma unroll
    for (int half = 0; half < 2; ++half) {
      int c = bcq + half * 64;
      int gc = bn + c;
      float4 v = make_float4(0.f, 0.f, 0.f, 0.f);
      if (gc + 3 < N) v = *(const float4*)&W[(size_t)(k0 + bkk) * N + gc];
      *(float4*)&Bs[bkk][c] = v;
    }
    __syncthreads();
    #pragma unroll
    for (int kk = 0; kk < 16; ++kk) {
      float4 a0 = *(const float4*)&As[kk][ty * 4];
      float4 a1 = *(const float4*)&As[kk][ty * 4 + 64];
      float4 b0 = *(const float4*)&Bs[kk][tx * 4];
      float4 b1 = *(const float4*)&Bs[kk][tx * 4 + 64];
      float a[8] = {a0.x, a0.y, a0.z, a0.w, a1.x, a1.y, a1.z, a1.w};
      float b[8] = {b0.x, b0.y, b0.z, b0.w, b1.x, b1.y, b1.z, b1.w};
      #pragma unroll
      for (int i = 0; i < 8; ++i)
        #pragma unroll
        for (int j = 0; j < 8; ++j) acc[i][j] = fmaf(a[i], b[j], acc[i][j]);
    }
    __syncthreads();
  }

  #pragma unroll
  for (int i = 0; i < 8; ++i) {
    int r = bm + (i < 4 ? ty * 4 + i : 64 + ty * 4 + (i - 4));
    if (r >= M) continue;
    #pragma unroll
    for (int j = 0; j < 8; ++j) {
      int c = bn + (j < 4 ? tx * 4 + j : 64 + tx * 4 + (j - 4));
      if (c >= N) continue;
      float v = acc[i][j];
      if (BIASRELU) {
        v += bias[c];
        v = v > 0.f ? v : 0.f;
      }
      C[(size_t)r * N + c] = v;
    }
  }
}

// ---------------- launch ----------------

extern "C" void kernel_launch(void* const* d_in, const int* in_sizes, int n_in,
                              void* d_out, int out_size, void* d_ws, size_t ws_size,
                              hipStream_t stream) {
  const float* x  = (const float*)d_in[0];
  const int* src  = (const int*)d_in[1];
  const int* dst  = (const int*)d_in[2];
  const float* W1 = (const float*)d_in[3];
  const float* b1 = (const float*)d_in[4];
  const float* W2 = (const float*)d_in[5];
  const float* b2 = (const float*)d_in[6];
  const float* W3 = (const float*)d_in[7];
  const float* b3 = (const float*)d_in[8];
  const float* W4 = (const float*)d_in[9];
  const float* b4 = (const float*)d_in[10];
  float* out = (float*)d_out;

  const int N = GCN_N, E = GCN_E;

  char* ws = (char*)d_ws;
  size_t off = 0;
  float* bufF = (float*)(ws + off); off += (size_t)N * 512 * 4;       // fp32 h buffer
  u16* sHi    = (u16*)(ws + off);   off += (size_t)N * 512 * 2;       // split hi
  u16* sLo    = (u16*)(ws + off);   off += (size_t)N * 512 * 2;       // split lo
  float* c_src = (float*)(ws + off); off += (size_t)N * 4;
  float* c_dst = (float*)(ws + off); off += (size_t)N * 4;
  int* row_ptr = (int*)(ws + off); off += (size_t)(N + 4) * 4;
  int* csr_src = (int*)(ws + off); off += (size_t)E * 4;
  u16* WtH1 = (u16*)(ws + off); off += (size_t)512 * 256 * 2;
  u16* WtL1 = (u16*)(ws + off); off += (size_t)512 * 256 * 2;
  u16* WtH2 = (u16*)(ws + off); off += (size_t)512 * 512 * 2;
  u16* WtL2 = (u16*)(ws + off); off += (size_t)512 * 512 * 2;
  u16* WtH3 = (u16*)(ws + off); off += (size_t)512 * 512 * 2;
  u16* WtL3 = (u16*)(ws + off); off += (size_t)512 * 512 * 2;
  // transients: deg/cursor alias bufF (dead before gemm1 writes bufF)
  int* deg_src = (int*)bufF;
  int* deg_dst = deg_src + N;
  int* cursor  = deg_dst + N;
  // t4 [N][40] fp32 aliases sHi space (free by layer 4)
  float* t4 = (float*)sHi;

  hipMemsetAsync(deg_src, 0, (size_t)2 * N * 4, stream);
  hist_kernel<<<(E + 255) / 256, 256, 0, stream>>>(src, dst, deg_src, deg_dst, E);
  cinv_kernel<<<(N + 255) / 256, 256, 0, stream>>>(deg_src, deg_dst, c_src, c_dst, N);
  scan_kernel<<<1, 1024, 0, stream>>>(deg_dst, row_ptr, cursor, N);
  fill_csr_kernel<<<(E + 255) / 256, 256, 0, stream>>>(src, dst, cursor, csr_src, E);

  prep_weight_kernel<<<dim3(16, 8), dim3(32, 8), 0, stream>>>(W1, WtH1, WtL1, 256, 512);
  prep_weight_kernel<<<dim3(16, 16), dim3(32, 8), 0, stream>>>(W2, WtH2, WtL2, 512, 512);
  prep_weight_kernel<<<dim3(16, 16), dim3(32, 8), 0, stream>>>(W3, WtH3, WtL3, 512, 512);

  int gm = (N + 127) / 128;  // 391

  // L1
  agg_split_kernel<<<N, 64, 0, stream>>>(x, sHi, sLo, row_ptr, csr_src, c_src, c_dst, 64);
  mfma_gemm_kernel<<<dim3(gm, 4), 256, 0, stream>>>(sHi, sLo, WtH1, WtL1, b1, bufF, N, 256, 512);
  // L2
  agg_split_kernel<<<N, 128, 0, stream>>>(bufF, sHi, sLo, row_ptr, csr_src, c_src, c_dst, 128);
  mfma_gemm_kernel<<<dim3(gm, 4), 256, 0, stream>>>(sHi, sLo, WtH2, WtL2, b2, bufF, N, 512, 512);
  // L3
  agg_split_kernel<<<N, 128, 0, stream>>>(bufF, sHi, sLo, row_ptr, csr_src, c_src, c_dst, 128);
  mfma_gemm_kernel<<<dim3(gm, 4), 256, 0, stream>>>(sHi, sLo, WtH3, WtL3, b3, bufF, N, 512, 512);
  // L4
  gemm_kernel<false><<<dim3(gm, 1), 256, 0, stream>>>(bufF, W4, nullptr, t4, N, 512, 40);
  aggregate_kernel<true><<<N, 64, 0, stream>>>(t4, out, row_ptr, csr_src, c_src, c_dst, b4, 10);
}

// Round 6
// 1044.892 us; speedup vs baseline: 1.8104x; 1.2544x over previous
//
#include <hip/hip_runtime.h>
#include <hip/hip_bf16.h>

// ---------------------------------------------------------------------------
// GCN forward, 4x GraphConv norm='both'. N=50000, E=800000, 256->512->512->512->40
// R3 (re-run; previous three benches were infra failures — capacity/container):
// inter-layer activations stored fp16 (halves gather traffic); aggregation
// gathers fp16, accumulates fp32, emits split-bf16 hi/lo for MFMA GEMMs.
// ---------------------------------------------------------------------------

#define GCN_N 50000
#define GCN_E 800000

typedef unsigned short u16;
typedef __attribute__((ext_vector_type(8))) short bf16x8;
typedef __attribute__((ext_vector_type(4))) float f32x4;
typedef __attribute__((ext_vector_type(4))) _Float16 f16x4;

__device__ __forceinline__ void gload_lds16(const void* g, void* l) {
  __builtin_amdgcn_global_load_lds((const __attribute__((address_space(1))) void*)g,
                                   (__attribute__((address_space(3))) void*)l, 16, 0, 0);
}

__device__ __forceinline__ void bsplit(float v, u16& h, u16& l) {
  __hip_bfloat16 bh = __float2bfloat16(v);   // RNE
  float fh = __bfloat162float(bh);
  __hip_bfloat16 bl = __float2bfloat16(v - fh);
  h = __builtin_bit_cast(u16, bh);
  l = __builtin_bit_cast(u16, bl);
}

// ---------------- CSR build ----------------

__global__ void hist_kernel(const int* __restrict__ src, const int* __restrict__ dst,
                            int* __restrict__ deg_src, int* __restrict__ deg_dst, int E) {
  int i = blockIdx.x * blockDim.x + threadIdx.x;
  if (i < E) {
    atomicAdd(&deg_src[src[i]], 1);
    atomicAdd(&deg_dst[dst[i]], 1);
  }
}

__global__ void cinv_kernel(const int* __restrict__ deg_src, const int* __restrict__ deg_dst,
                            float* __restrict__ c_src, float* __restrict__ c_dst, int n) {
  int i = blockIdx.x * blockDim.x + threadIdx.x;
  if (i < n) {
    int ds = deg_src[i];
    int dd = deg_dst[i];
    c_src[i] = ds > 0 ? 1.0f / sqrtf((float)ds) : 0.0f;
    c_dst[i] = dd > 0 ? 1.0f / sqrtf((float)dd) : 0.0f;
  }
}

__global__ void scan_kernel(const int* __restrict__ deg, int* __restrict__ row_ptr,
                            int* __restrict__ cursor, int n) {
  __shared__ int wsum[16];
  __shared__ int s_carry;
  int lane = threadIdx.x & 63;
  int wid = threadIdx.x >> 6;
  if (threadIdx.x == 0) s_carry = 0;
  __syncthreads();
  for (int base = 0; base < n; base += 1024) {
    int i = base + (int)threadIdx.x;
    int v = (i < n) ? deg[i] : 0;
    int x = v;
    #pragma unroll
    for (int off = 1; off < 64; off <<= 1) {
      int y = __shfl_up(x, off, 64);
      if (lane >= off) x += y;
    }
    if (lane == 63) wsum[wid] = x;
    __syncthreads();
    int woff = s_carry;
    for (int w = 0; w < wid; ++w) woff += wsum[w];
    int incl = woff + x;
    if (i < n) {
      row_ptr[i] = incl - v;
      cursor[i] = incl - v;
    }
    __syncthreads();
    if (threadIdx.x == 1023) s_carry = incl;
    __syncthreads();
  }
  if (threadIdx.x == 0) row_ptr[n] = s_carry;
}

__global__ void fill_csr_kernel(const int* __restrict__ src, const int* __restrict__ dst,
                                int* __restrict__ cursor, int* __restrict__ csr_src, int E) {
  int i = blockIdx.x * blockDim.x + threadIdx.x;
  if (i < E) {
    int slot = atomicAdd(&cursor[dst[i]], 1);
    csr_src[slot] = src[i];
  }
}

// ---------------- fp32 -> fp16 convert ----------------

__global__ void f32_to_f16_kernel(const float* __restrict__ in, _Float16* __restrict__ out,
                                  long n4) {
  long i = (long)blockIdx.x * blockDim.x + threadIdx.x;
  long stride = (long)gridDim.x * blockDim.x;
  for (; i < n4; i += stride) {
    float4 v = ((const float4*)in)[i];
    f16x4 h;
    h.x = (_Float16)v.x; h.y = (_Float16)v.y; h.z = (_Float16)v.z; h.w = (_Float16)v.w;
    ((f16x4*)out)[i] = h;
  }
}

// ---------------- aggregation (fp16 in, fp32 accum) ----------------

// fp16 in -> split bf16 hi/lo out. One block per dst; thread t owns f16x4 group t.
// 1-deep index/coeff prefetch to keep two row-gathers in flight.
__global__ void agg_split16_kernel(const _Float16* __restrict__ in,
                                   u16* __restrict__ oh, u16* __restrict__ ol,
                                   const int* __restrict__ row_ptr, const int* __restrict__ csr_src,
                                   const float* __restrict__ c_src, const float* __restrict__ c_dst,
                                   int F4) {
  int d = blockIdx.x;
  int t = threadIdx.x;
  if (t >= F4) return;
  int beg = row_ptr[d];
  int end = row_ptr[d + 1];
  const f16x4* in4 = (const f16x4*)in;
  float ax = 0.f, ay = 0.f, az = 0.f, aw = 0.f;
  int s_cur = 0; float c_cur = 0.f;
  if (beg < end) { s_cur = csr_src[beg]; c_cur = c_src[s_cur]; }
  for (int k = beg; k < end; ++k) {
    int s_nxt = 0; float c_nxt = 0.f;
    if (k + 1 < end) { s_nxt = csr_src[k + 1]; c_nxt = c_src[s_nxt]; }
    f16x4 v = in4[(size_t)s_cur * F4 + t];
    ax = fmaf(c_cur, (float)v.x, ax);
    ay = fmaf(c_cur, (float)v.y, ay);
    az = fmaf(c_cur, (float)v.z, az);
    aw = fmaf(c_cur, (float)v.w, aw);
    s_cur = s_nxt; c_cur = c_nxt;
  }
  float cd = c_dst[d];
  ax *= cd; ay *= cd; az *= cd; aw *= cd;
  ushort4 hv, lv;
  bsplit(ax, hv.x, lv.x);
  bsplit(ay, hv.y, lv.y);
  bsplit(az, hv.z, lv.z);
  bsplit(aw, hv.w, lv.w);
  ((ushort4*)oh)[(size_t)d * F4 + t] = hv;
  ((ushort4*)ol)[(size_t)d * F4 + t] = lv;
}

// fp16 in -> fp32 out with bias (final 40-dim aggregation).
__global__ void agg16_bias_kernel(const _Float16* __restrict__ in, float* __restrict__ out,
                                  const int* __restrict__ row_ptr, const int* __restrict__ csr_src,
                                  const float* __restrict__ c_src, const float* __restrict__ c_dst,
                                  const float* __restrict__ bias, int F4) {
  int d = blockIdx.x;
  int t = threadIdx.x;
  if (t >= F4) return;
  int beg = row_ptr[d];
  int end = row_ptr[d + 1];
  const f16x4* in4 = (const f16x4*)in;
  float ax = 0.f, ay = 0.f, az = 0.f, aw = 0.f;
  int s_cur = 0; float c_cur = 0.f;
  if (beg < end) { s_cur = csr_src[beg]; c_cur = c_src[s_cur]; }
  for (int k = beg; k < end; ++k) {
    int s_nxt = 0; float c_nxt = 0.f;
    if (k + 1 < end) { s_nxt = csr_src[k + 1]; c_nxt = c_src[s_nxt]; }
    f16x4 v = in4[(size_t)s_cur * F4 + t];
    ax = fmaf(c_cur, (float)v.x, ax);
    ay = fmaf(c_cur, (float)v.y, ay);
    az = fmaf(c_cur, (float)v.z, az);
    aw = fmaf(c_cur, (float)v.w, aw);
    s_cur = s_nxt; c_cur = c_nxt;
  }
  float cd = c_dst[d];
  float4 b = ((const float4*)bias)[t];
  float4 o;
  o.x = ax * cd + b.x;
  o.y = ay * cd + b.y;
  o.z = az * cd + b.z;
  o.w = aw * cd + b.w;
  ((float4*)out)[(size_t)d * F4 + t] = o;
}

// ---------------- weight prep: W[K][N] fp32 -> Wt_hi/lo[N][K] bf16 ----------------

__global__ void prep_weight_kernel(const float* __restrict__ W, u16* __restrict__ th,
                                   u16* __restrict__ tl, int K, int N) {
  __shared__ float tile[32][33];
  int bn = blockIdx.x * 32, bk = blockIdx.y * 32;
  int tx = threadIdx.x, ty = threadIdx.y;  // (32, 8)
  #pragma unroll
  for (int i = 0; i < 4; ++i)
    tile[ty + i * 8][tx] = W[(size_t)(bk + ty + i * 8) * N + bn + tx];
  __syncthreads();
  #pragma unroll
  for (int i = 0; i < 4; ++i) {
    float v = tile[tx][ty + i * 8];           // = W[bk+tx][bn+ty+i*8]
    u16 h, l;
    bsplit(v, h, l);
    size_t o = (size_t)(bn + ty + i * 8) * K + bk + tx;  // Wt[n][k]
    th[o] = h;
    tl[o] = l;
  }
}

// ---------------- split-bf16 MFMA GEMM (fp16 output) ----------------
// C16[M][N] = relu( (Ah+Al)[M][K] * (Bh+Bl)^T[N][K] + bias ), 3-term MFMA.
__global__ __launch_bounds__(256) void mfma_gemm_kernel(
    const u16* __restrict__ Ah, const u16* __restrict__ Al,
    const u16* __restrict__ Bh, const u16* __restrict__ Bl,
    const float* __restrict__ bias, _Float16* __restrict__ C,
    int M, int K, int N) {
  __shared__ u16 sAh[128 * 32], sAl[128 * 32], sBh[128 * 32], sBl[128 * 32];
  int t = threadIdx.x;
  int lane = t & 63, wid = t >> 6;
  int wr = wid >> 1, wc = wid & 1;
  int lr = lane & 15, ko = lane >> 4;
  int swz = (lr & 3) ^ ((lr >> 2) & 3);
  int koff = ((ko ^ swz) << 3);
  int bm = blockIdx.x * 128, bn = blockIdx.y * 128;

  f32x4 acc[4][4] = {};

  int aoff[4], boff[4];
  #pragma unroll
  for (int rb = 0; rb < 4; ++rb) {
    aoff[rb] = (wr * 64 + rb * 16 + lr) * 32 + koff;
    boff[rb] = (wc * 64 + rb * 16 + lr) * 32 + koff;
  }

  for (int k0 = 0; k0 < K; k0 += 32) {
    #pragma unroll
    for (int it = 0; it < 2; ++it) {
      int q = it * 256 + t;
      int row = q >> 2;
      int c = (q & 3) ^ ((row & 3) ^ ((row >> 2) & 3));
      int ldst = it * 2048 + wid * 512;
      int gra = bm + row;
      if (gra >= M) gra = M - 1;
      size_t ga = (size_t)gra * K + k0 + c * 8;
      gload_lds16(Ah + ga, sAh + ldst);
      gload_lds16(Al + ga, sAl + ldst);
      size_t gb = (size_t)(bn + row) * K + k0 + c * 8;
      gload_lds16(Bh + gb, sBh + ldst);
      gload_lds16(Bl + gb, sBl + ldst);
    }
    __syncthreads();
    bf16x8 ah[4], al[4], bh[4], bl[4];
    #pragma unroll
    for (int i = 0; i < 4; ++i) {
      ah[i] = *(const bf16x8*)(sAh + aoff[i]);
      al[i] = *(const bf16x8*)(sAl + aoff[i]);
      bh[i] = *(const bf16x8*)(sBh + boff[i]);
      bl[i] = *(const bf16x8*)(sBl + boff[i]);
    }
    #pragma unroll
    for (int i = 0; i < 4; ++i)
      #pragma unroll
      for (int j = 0; j < 4; ++j) {
        acc[i][j] = __builtin_amdgcn_mfma_f32_16x16x32_bf16(ah[i], bh[j], acc[i][j], 0, 0, 0);
        acc[i][j] = __builtin_amdgcn_mfma_f32_16x16x32_bf16(al[i], bh[j], acc[i][j], 0, 0, 0);
        acc[i][j] = __builtin_amdgcn_mfma_f32_16x16x32_bf16(ah[i], bl[j], acc[i][j], 0, 0, 0);
      }
    __syncthreads();
  }

  int r0 = (lane >> 4) << 2;
  #pragma unroll
  for (int i = 0; i < 4; ++i) {
    #pragma unroll
    for (int j = 0; j < 4; ++j) {
      int col = bn + wc * 64 + j * 16 + lr;
      float bv = bias[col];
      #pragma unroll
      for (int r = 0; r < 4; ++r) {
        int row = bm + wr * 64 + i * 16 + r0 + r;
        if (row < M) {
          float v = acc[i][j][r] + bv;
          v = v > 0.f ? v : 0.f;
          C[(size_t)row * N + col] = (_Float16)v;
        }
      }
    }
  }
}

// ---------------- fp32 VALU GEMM, fp16 A and C (layer 4, N=40) ----------------

__global__ __launch_bounds__(256) void gemm40_kernel(const _Float16* __restrict__ A,
                                                     const float* __restrict__ W,
                                                     _Float16* __restrict__ C,
                                                     int M, int K, int N) {
  __shared__ float As[16][128 + 4];
  __shared__ float Bs[16][128 + 4];
  int tid = threadIdx.x;
  int tx = tid & 15;
  int ty = tid >> 4;
  int bm = blockIdx.x * 128;
  int bn = blockIdx.y * 128;

  float acc[8][8];
  #pragma unroll
  for (int i = 0; i < 8; ++i)
    #pragma unroll
    for (int j = 0; j < 8; ++j) acc[i][j] = 0.f;

  int ar = tid >> 2;
  int akq = (tid & 3) << 2;
  int bkk = tid >> 4;
  int bcq = (tid & 15) << 2;

  for (int k0 = 0; k0 < K; k0 += 16) {
    #pragma unroll
    for (int half = 0; half < 2; ++half) {
      int r = ar + half * 64;
      int grow = bm + r;
      float4 v = make_float4(0.f, 0.f, 0.f, 0.f);
      if (grow < M) {
        f16x4 hv = *(const f16x4*)&A[(size_t)grow * K + k0 + akq];
        v = make_float4((float)hv.x, (float)hv.y, (float)hv.z, (float)hv.w);
      }
      As[akq + 0][r] = v.x;
      As[akq + 1][r] = v.y;
      As[akq + 2][r] = v.z;
      As[akq + 3][r] = v.w;
    }
    #pragma unroll
    for (int half = 0; half < 2; ++half) {
      int c = bcq + half * 64;
      int gc = bn + c;
      float4 v = make_float4(0.f, 0.f, 0.f, 0.f);
      if (gc + 3 < N) v = *(const float4*)&W[(size_t)(k0 + bkk) * N + gc];
      *(float4*)&Bs[bkk][c] = v;
    }
    __syncthreads();
    #pragma unroll
    for (int kk = 0; kk < 16; ++kk) {
      float4 a0 = *(const float4*)&As[kk][ty * 4];
      float4 a1 = *(const float4*)&As[kk][ty * 4 + 64];
      float4 b0 = *(const float4*)&Bs[kk][tx * 4];
      float4 b1 = *(const float4*)&Bs[kk][tx * 4 + 64];
      float a[8] = {a0.x, a0.y, a0.z, a0.w, a1.x, a1.y, a1.z, a1.w};
      float b[8] = {b0.x, b0.y, b0.z, b0.w, b1.x, b1.y, b1.z, b1.w};
      #pragma unroll
      for (int i = 0; i < 8; ++i)
        #pragma unroll
        for (int j = 0; j < 8; ++j) acc[i][j] = fmaf(a[i], b[j], acc[i][j]);
    }
    __syncthreads();
  }

  #pragma unroll
  for (int i = 0; i < 8; ++i) {
    int r = bm + (i < 4 ? ty * 4 + i : 64 + ty * 4 + (i - 4));
    if (r >= M) continue;
    #pragma unroll
    for (int j = 0; j < 8; ++j) {
      int c = bn + (j < 4 ? tx * 4 + j : 64 + tx * 4 + (j - 4));
      if (c >= N) continue;
      C[(size_t)r * N + c] = (_Float16)acc[i][j];
    }
  }
}

// ---------------- launch ----------------

extern "C" void kernel_launch(void* const* d_in, const int* in_sizes, int n_in,
                              void* d_out, int out_size, void* d_ws, size_t ws_size,
                              hipStream_t stream) {
  const float* x  = (const float*)d_in[0];
  const int* src  = (const int*)d_in[1];
  const int* dst  = (const int*)d_in[2];
  const float* W1 = (const float*)d_in[3];
  const float* b1 = (const float*)d_in[4];
  const float* W2 = (const float*)d_in[5];
  const float* b2 = (const float*)d_in[6];
  const float* W3 = (const float*)d_in[7];
  const float* b3 = (const float*)d_in[8];
  const float* W4 = (const float*)d_in[9];
  const float* b4 = (const float*)d_in[10];
  float* out = (float*)d_out;

  const int N = GCN_N, E = GCN_E;

  char* ws = (char*)d_ws;
  size_t off = 0;
  u16* sHi = (u16*)(ws + off); off += (size_t)N * 512 * 2;
  u16* sLo = (u16*)(ws + off); off += (size_t)N * 512 * 2;
  _Float16* h16 = (_Float16*)(ws + off); off += (size_t)N * 512 * 2;
  _Float16* x16 = (_Float16*)(ws + off); off += (size_t)N * 256 * 2;
  float* c_src = (float*)(ws + off); off += (size_t)N * 4;
  float* c_dst = (float*)(ws + off); off += (size_t)N * 4;
  int* row_ptr = (int*)(ws + off); off += (size_t)(N + 4) * 4;
  int* csr_src = (int*)(ws + off); off += (size_t)E * 4;
  u16* WtH1 = (u16*)(ws + off); off += (size_t)512 * 256 * 2;
  u16* WtL1 = (u16*)(ws + off); off += (size_t)512 * 256 * 2;
  u16* WtH2 = (u16*)(ws + off); off += (size_t)512 * 512 * 2;
  u16* WtL2 = (u16*)(ws + off); off += (size_t)512 * 512 * 2;
  u16* WtH3 = (u16*)(ws + off); off += (size_t)512 * 512 * 2;
  u16* WtL3 = (u16*)(ws + off); off += (size_t)512 * 512 * 2;
  // transients alias sHi (dead before L1 agg writes sHi)
  int* deg_src = (int*)sHi;
  int* deg_dst = deg_src + N;
  int* cursor  = deg_dst + N;
  // t4 [N][40] fp16 aliases x16 (x16 dead after L1 agg)
  _Float16* t4 = x16;

  hipMemsetAsync(deg_src, 0, (size_t)2 * N * 4, stream);
  hist_kernel<<<(E + 255) / 256, 256, 0, stream>>>(src, dst, deg_src, deg_dst, E);
  cinv_kernel<<<(N + 255) / 256, 256, 0, stream>>>(deg_src, deg_dst, c_src, c_dst, N);
  scan_kernel<<<1, 1024, 0, stream>>>(deg_dst, row_ptr, cursor, N);
  fill_csr_kernel<<<(E + 255) / 256, 256, 0, stream>>>(src, dst, cursor, csr_src, E);

  prep_weight_kernel<<<dim3(16, 8), dim3(32, 8), 0, stream>>>(W1, WtH1, WtL1, 256, 512);
  prep_weight_kernel<<<dim3(16, 16), dim3(32, 8), 0, stream>>>(W2, WtH2, WtL2, 512, 512);
  prep_weight_kernel<<<dim3(16, 16), dim3(32, 8), 0, stream>>>(W3, WtH3, WtL3, 512, 512);

  f32_to_f16_kernel<<<2048, 256, 0, stream>>>(x, x16, (long)N * 256 / 4);

  int gm = (N + 127) / 128;  // 391

  // L1
  agg_split16_kernel<<<N, 64, 0, stream>>>(x16, sHi, sLo, row_ptr, csr_src, c_src, c_dst, 64);
  mfma_gemm_kernel<<<dim3(gm, 4), 256, 0, stream>>>(sHi, sLo, WtH1, WtL1, b1, h16, N, 256, 512);
  // L2
  agg_split16_kernel<<<N, 128, 0, stream>>>(h16, sHi, sLo, row_ptr, csr_src, c_src, c_dst, 128);
  mfma_gemm_kernel<<<dim3(gm, 4), 256, 0, stream>>>(sHi, sLo, WtH2, WtL2, b2, h16, N, 512, 512);
  // L3
  agg_split16_kernel<<<N, 128, 0, stream>>>(h16, sHi, sLo, row_ptr, csr_src, c_src, c_dst, 128);
  mfma_gemm_kernel<<<dim3(gm, 4), 256, 0, stream>>>(sHi, sLo, WtH3, WtL3, b3, h16, N, 512, 512);
  // L4
  gemm40_kernel<<<dim3(gm, 1), 256, 0, stream>>>(h16, W4, t4, N, 512, 40);
  agg16_bias_kernel<<<N, 64, 0, stream>>>(t4, out, row_ptr, csr_src, c_src, c_dst, b4, 10);
}